// Round 8
// baseline (45.466 us; speedup 1.0000x reference)
//
#include <hip/hip_runtime.h>
#include <hip/hip_bf16.h>

#define MROWS 65536
#define DD 768
#define HH 64

typedef __attribute__((ext_vector_type(8))) short short8;
typedef __attribute__((ext_vector_type(4))) float f32x4;

// f32 -> bf16 round-to-nearest-even (bit trick; NaN irrelevant for this data)
__device__ inline unsigned short f2bf(float x) {
    union { float f; unsigned u; } v; v.f = x;
    unsigned r = v.u + 0x7fffu + ((v.u >> 16) & 1u);
    return (unsigned short)(r >> 16);
}

// identity buckets <=4, floor(log2)+3 above, clamped [0,9] (exact int version)
__device__ inline int bucket(int c) {
    int idx = (c <= 4) ? c : (34 - __clz(c));   // 31 - clz + 3
    idx = idx < 0 ? 0 : idx;
    return idx > 9 ? 9 : idx;
}

// A/B fragment k-map: lane (g = lane>>4, c0 = lane&15), reg j in [0,8):
//   k = (j>>2)*16 + g*4 + (j&3)      (bijective on [0,32))
// a0 covers bytes [0,64) of the row's 128-B k-chunk, a1 covers [64,128).
// NOTE: __builtin_nontemporal_load on the A-stream is ~35% SLOWER regardless
// of k-map (measured rounds 2 and 6) -- never reintroduce it.
//
// ws layout:
//   Wf    : bf16[24][4][64][8]  = 49152 ushort  (98304 B)  -- W_eff in B-fragment order
//   constv: f32[64]             @ 98304          -- b1 + ment @ W1[768:1536]
//   dlut  : f32[10][64]         @ 98560          -- dist_table @ W1[2304:2324]
//   clut  : f32[10][64]         @ 101120         -- counter_table @ W1[2324:2344]
__global__ __launch_bounds__(1024) void precompute_kernel(
                                  const float* __restrict__ ment,
                                  const float* __restrict__ dist_t,
                                  const float* __restrict__ cnt_t,
                                  const float* __restrict__ W1,
                                  const float* __restrict__ b1,
                                  unsigned short* __restrict__ Wf,
                                  float* __restrict__ constv,
                                  float* __restrict__ dlut,
                                  float* __restrict__ clut) {
    __shared__ float red[1024];
    int b = blockIdx.x;
    if (b < 24) {
        // pack W_eff for k-step s = b: W_eff[d][h] = W1[d][h] + ment[d]*W1[1536+d][h]
        int s = b;
        for (int e = threadIdx.x; e < 2048; e += blockDim.x) {
            int t    = e >> 9;          // n-tile 0..3
            int lane = (e >> 3) & 63;
            int j    = e & 7;
            int d = s * 32 + ((j >> 2) << 4) + (((lane >> 4) & 3) << 2) + (j & 3);
            int h = t * 16 + (lane & 15);
            float v = W1[d * HH + h] + ment[d] * W1[(1536 + d) * HH + h];
            Wf[(size_t)((s * 4 + t) * 64 + lane) * 8 + j] = f2bf(v);
        }
    } else if (b == 24) {
        // constv[h] = b1[h] + sum_d ment[d] * W1[768+d][h]
        // 1024 threads = 64 h x 16 chunks of 48 d each; LDS tree at the end.
        int h = threadIdx.x & 63;
        int chunk = threadIdx.x >> 6;            // 0..15
        float acc = 0.f;
        #pragma unroll 8
        for (int d = chunk * 48; d < chunk * 48 + 48; ++d)
            acc += ment[d] * W1[(768 + d) * HH + h];
        red[threadIdx.x] = acc;
        __syncthreads();
        if (chunk == 0) {
            float s0 = b1[h];
            #pragma unroll
            for (int k = 0; k < 16; ++k) s0 += red[k * 64 + h];
            constv[h] = s0;
        }
    } else if (b == 25) {
        for (int e = threadIdx.x; e < 640; e += blockDim.x) {
            int tt = e >> 6, h = e & 63;
            float a = 0.f;
            #pragma unroll
            for (int k = 0; k < 20; ++k)
                a += dist_t[tt * 20 + k] * W1[(2304 + k) * HH + h];
            dlut[e] = a;
        }
    } else if (b == 26) {
        for (int e = threadIdx.x; e < 640; e += blockDim.x) {
            int tt = e >> 6, h = e & 63;
            float a = 0.f;
            #pragma unroll
            for (int k = 0; k < 20; ++k)
                a += cnt_t[tt * 20 + k] * W1[(2324 + k) * HH + h];
            clut[e] = a;
        }
    }
}

// 32 rows per wave, 512 blocks x 4 waves, no LDS, no barriers.
// Round 8: double-buffered register staging (stA/stB) -- super-step ss+1's
// 16 A-loads issue BEFORE computing ss, so each wave keeps ~16 loads
// outstanding continuously instead of a ~50% duty cycle (register-space T14).
// All staging indices compile-time (macro-expanded full unroll).

#define LOADSS(BUF, SS) do {                                          \
    _Pragma("unroll")                                                 \
    for (int q = 0; q < 4; ++q) {                                     \
        const float* p0 = arow0 + ((SS) * 4 + q) * 32;                \
        const float* p1 = arow1 + ((SS) * 4 + q) * 32;                \
        BUF[q * 4 + 0] = *(const f32x4*)(p0);                         \
        BUF[q * 4 + 1] = *(const f32x4*)(p0 + 16);                    \
        BUF[q * 4 + 2] = *(const f32x4*)(p1);                         \
        BUF[q * 4 + 3] = *(const f32x4*)(p1 + 16);                    \
    }                                                                 \
} while (0)

#define COMPSS(BUF, SS) do {                                          \
    _Pragma("unroll")                                                 \
    for (int q = 0; q < 4; ++q) {                                     \
        f32x4 a0 = BUF[q * 4 + 0], a1 = BUF[q * 4 + 1];               \
        f32x4 d0 = BUF[q * 4 + 2], d1 = BUF[q * 4 + 3];               \
        short8 afA, afB;                                              \
        afA[0] = (short)f2bf(a0[0]); afA[1] = (short)f2bf(a0[1]);     \
        afA[2] = (short)f2bf(a0[2]); afA[3] = (short)f2bf(a0[3]);     \
        afA[4] = (short)f2bf(a1[0]); afA[5] = (short)f2bf(a1[1]);     \
        afA[6] = (short)f2bf(a1[2]); afA[7] = (short)f2bf(a1[3]);     \
        afB[0] = (short)f2bf(d0[0]); afB[1] = (short)f2bf(d0[1]);     \
        afB[2] = (short)f2bf(d0[2]); afB[3] = (short)f2bf(d0[3]);     \
        afB[4] = (short)f2bf(d1[0]); afB[5] = (short)f2bf(d1[1]);     \
        afB[6] = (short)f2bf(d1[2]); afB[7] = (short)f2bf(d1[3]);     \
        const unsigned short* bp = Wf + (size_t)((SS) * 4 + q) * 2048 + lane * 8; \
        short8 bf0 = *(const short8*)(bp);                            \
        short8 bf1 = *(const short8*)(bp + 512);                      \
        short8 bf2 = *(const short8*)(bp + 1024);                     \
        short8 bf3 = *(const short8*)(bp + 1536);                     \
        acc[0][0] = __builtin_amdgcn_mfma_f32_16x16x32_bf16(afA, bf0, acc[0][0], 0, 0, 0); \
        acc[0][1] = __builtin_amdgcn_mfma_f32_16x16x32_bf16(afA, bf1, acc[0][1], 0, 0, 0); \
        acc[0][2] = __builtin_amdgcn_mfma_f32_16x16x32_bf16(afA, bf2, acc[0][2], 0, 0, 0); \
        acc[0][3] = __builtin_amdgcn_mfma_f32_16x16x32_bf16(afA, bf3, acc[0][3], 0, 0, 0); \
        acc[1][0] = __builtin_amdgcn_mfma_f32_16x16x32_bf16(afB, bf0, acc[1][0], 0, 0, 0); \
        acc[1][1] = __builtin_amdgcn_mfma_f32_16x16x32_bf16(afB, bf1, acc[1][1], 0, 0, 0); \
        acc[1][2] = __builtin_amdgcn_mfma_f32_16x16x32_bf16(afB, bf2, acc[1][2], 0, 0, 0); \
        acc[1][3] = __builtin_amdgcn_mfma_f32_16x16x32_bf16(afB, bf3, acc[1][3], 0, 0, 0); \
    }                                                                 \
} while (0)

__global__ __launch_bounds__(256, 2) void score_kernel(
    const float* __restrict__ mem,
    const unsigned short* __restrict__ Wf,
    const float* __restrict__ constv,
    const float* __restrict__ dlut,
    const float* __restrict__ clut,
    const float* __restrict__ W2,
    const float* __restrict__ b2p,
    const int* __restrict__ entc,
    const int* __restrict__ lms,
    const int* __restrict__ msp,
    float* __restrict__ out) {

    int wave = threadIdx.x >> 6;
    int lane = threadIdx.x & 63;
    int g  = lane >> 4;     // 0..3
    int c0 = lane & 15;     // 0..15
    int row0 = blockIdx.x * 128 + wave * 32;    // wave's first row (32 rows)

    if (blockIdx.x == 0 && threadIdx.x == 0) out[MROWS] = 0.0f;  // dummy new-cluster score

    // A sources: row-set 0 = rows row0+c0, row-set 1 = rows row0+16+c0.
    const float* arow0 = mem + (size_t)(row0 + c0) * DD + g * 4;
    const float* arow1 = arow0 + (size_t)16 * DD;

    f32x4 acc[2][4];
    #pragma unroll
    for (int r = 0; r < 2; ++r)
        #pragma unroll
        for (int t = 0; t < 4; ++t)
            acc[r][t] = (f32x4){0.f, 0.f, 0.f, 0.f};

    f32x4 stA[16], stB[16];
    // Software pipeline over 6 super-steps: load ss+1 before computing ss.
    LOADSS(stA, 0);
    LOADSS(stB, 1); COMPSS(stA, 0);
    LOADSS(stA, 2); COMPSS(stB, 1);
    LOADSS(stB, 3); COMPSS(stA, 2);
    LOADSS(stA, 4); COMPSS(stB, 3);
    LOADSS(stB, 5); COMPSS(stA, 4);
    COMPSS(stB, 5);

    // Epilogue. D layout (m89): col = lane&15 (h-tile col), row = g*4 + reg.
    int ms  = msp[0];
    float b2v = b2p[0];
    float cv[4], w2[4];
    #pragma unroll
    for (int t = 0; t < 4; ++t) {
        cv[t] = constv[t * 16 + c0];
        w2[t] = W2[t * 16 + c0];
    }

    #pragma unroll
    for (int r = 0; r < 2; ++r) {
        #pragma unroll
        for (int i = 0; i < 4; ++i) {
            int row = row0 + r * 16 + g * 4 + i;
            int c    = entc[row];
            int dist = ms - lms[row];
            int db = bucket(dist);
            int cb = bucket(c);
            float part = 0.f;
            #pragma unroll
            for (int t = 0; t < 4; ++t) {
                float a = acc[r][t][i];
                int hc = t * 16 + c0;
                float h = a + cv[t] + dlut[db * 64 + hc] + clut[cb * 64 + hc];
                h = fmaxf(h, 0.f);
                part += h * w2[t];
            }
            // reduce across the 16 lanes of this group (lanes share g)
            part += __shfl_xor(part, 8, 64);
            part += __shfl_xor(part, 4, 64);
            part += __shfl_xor(part, 2, 64);
            part += __shfl_xor(part, 1, 64);
            if (c0 == 0)
                out[row] = (c > 0) ? (part + b2v) : -10000.0f;
        }
    }
}

extern "C" void kernel_launch(void* const* d_in, const int* in_sizes, int n_in,
                              void* d_out, int out_size, void* d_ws, size_t ws_size,
                              hipStream_t stream) {
    const float* ment   = (const float*)d_in[0];
    const float* mem    = (const float*)d_in[1];
    const float* dist_t = (const float*)d_in[2];
    const float* cnt_t  = (const float*)d_in[3];
    const float* W1     = (const float*)d_in[4];
    const float* b1     = (const float*)d_in[5];
    const float* W2     = (const float*)d_in[6];
    const float* b2     = (const float*)d_in[7];
    const int*   entc   = (const int*)d_in[8];
    const int*   lmsp   = (const int*)d_in[9];
    const int*   msp    = (const int*)d_in[10];

    unsigned short* Wf = (unsigned short*)d_ws;
    float* constv = (float*)((char*)d_ws + 98304);
    float* dlut   = constv + 64;
    float* clut   = dlut + 640;

    precompute_kernel<<<27, 1024, 0, stream>>>(ment, dist_t, cnt_t, W1, b1, Wf, constv, dlut, clut);
    score_kernel<<<512, 256, 0, stream>>>(mem, Wf, constv, dlut, clut, W2, b2,
                                          entc, lmsp, msp, (float*)d_out);
}

// Round 9
// 42.637 us; speedup vs baseline: 1.0663x; 1.0663x over previous
//
#include <hip/hip_runtime.h>
#include <hip/hip_bf16.h>

#define MROWS 65536
#define DD 768
#define HH 64

typedef __attribute__((ext_vector_type(8))) short short8;
typedef __attribute__((ext_vector_type(4))) float f32x4;

// f32 -> bf16 round-to-nearest-even (bit trick; NaN irrelevant for this data)
__device__ inline unsigned short f2bf(float x) {
    union { float f; unsigned u; } v; v.f = x;
    unsigned r = v.u + 0x7fffu + ((v.u >> 16) & 1u);
    return (unsigned short)(r >> 16);
}

// identity buckets <=4, floor(log2)+3 above, clamped [0,9] (exact int version)
__device__ inline int bucket(int c) {
    int idx = (c <= 4) ? c : (34 - __clz(c));   // 31 - clz + 3
    idx = idx < 0 ? 0 : idx;
    return idx > 9 ? 9 : idx;
}

// A/B fragment k-map: lane (g = lane>>4, c0 = lane&15), reg j in [0,8):
//   k = (j>>2)*16 + g*4 + (j&3)      (bijective on [0,32))
// NOTE: __builtin_nontemporal_load on the A-stream is ~35% SLOWER regardless
// of k-map (measured rounds 2 and 6) -- never reintroduce it.
//
// ws layout:
//   Wf    : bf16[24][4][64][8]  = 49152 ushort  (98304 B)  -- W_eff in B-fragment order
//   constv: f32[64]             @ 98304          -- b1 + ment @ W1[768:1536]
//   dlut  : f32[10][64]         @ 98560          -- dist_table @ W1[2304:2324]
//   clut  : f32[10][64]         @ 101120         -- counter_table @ W1[2324:2344]
__global__ __launch_bounds__(1024) void precompute_kernel(
                                  const float* __restrict__ ment,
                                  const float* __restrict__ dist_t,
                                  const float* __restrict__ cnt_t,
                                  const float* __restrict__ W1,
                                  const float* __restrict__ b1,
                                  unsigned short* __restrict__ Wf,
                                  float* __restrict__ constv,
                                  float* __restrict__ dlut,
                                  float* __restrict__ clut) {
    __shared__ float red[1024];
    int b = blockIdx.x;
    if (b < 24) {
        int s = b;
        for (int e = threadIdx.x; e < 2048; e += blockDim.x) {
            int t    = e >> 9;          // n-tile 0..3
            int lane = (e >> 3) & 63;
            int j    = e & 7;
            int d = s * 32 + ((j >> 2) << 4) + (((lane >> 4) & 3) << 2) + (j & 3);
            int h = t * 16 + (lane & 15);
            float v = W1[d * HH + h] + ment[d] * W1[(1536 + d) * HH + h];
            Wf[(size_t)((s * 4 + t) * 64 + lane) * 8 + j] = f2bf(v);
        }
    } else if (b == 24) {
        int h = threadIdx.x & 63;
        int chunk = threadIdx.x >> 6;            // 0..15
        float acc = 0.f;
        #pragma unroll 8
        for (int d = chunk * 48; d < chunk * 48 + 48; ++d)
            acc += ment[d] * W1[(768 + d) * HH + h];
        red[threadIdx.x] = acc;
        __syncthreads();
        if (chunk == 0) {
            float s0 = b1[h];
            #pragma unroll
            for (int k = 0; k < 16; ++k) s0 += red[k * 64 + h];
            constv[h] = s0;
        }
    } else if (b == 25) {
        for (int e = threadIdx.x; e < 640; e += blockDim.x) {
            int tt = e >> 6, h = e & 63;
            float a = 0.f;
            #pragma unroll
            for (int k = 0; k < 20; ++k)
                a += dist_t[tt * 20 + k] * W1[(2304 + k) * HH + h];
            dlut[e] = a;
        }
    } else if (b == 26) {
        for (int e = threadIdx.x; e < 640; e += blockDim.x) {
            int tt = e >> 6, h = e & 63;
            float a = 0.f;
            #pragma unroll
            for (int k = 0; k < 20; ++k)
                a += cnt_t[tt * 20 + k] * W1[(2324 + k) * HH + h];
            clut[e] = a;
        }
    }
}

// Round 9: wave-private LDS redistribution so every A-load instruction is a
// fully CONTIGUOUS 64-lane 1-KB span (like the 7-TB/s memset reference),
// instead of 16 scattered 64-B sectors across 3072-B-strided rows.
// Per wave: 32 rows x 12 halves (2 k-steps = 256 B/row each). Contiguous
// global loads -> regs (2 halves in flight) -> ds_write_b128 into an
// XOR-swizzled [32][256] half-slab (2 slabs ping-pong) -> ds_read_b128
// fragments. Swizzle: inner ^ ((row&7)<<4) -- bank-uniform on both sides.
// No barriers (slab is wave-private); compiler tracks all waits.

#define GLOADA(RBUF, H) do {                                            \
    _Pragma("unroll")                                                   \
    for (int t = 0; t < 8; ++t)                                         \
        RBUF[t] = *(const f32x4*)(gA + (size_t)t * 12288 + (size_t)(H) * 256); \
} while (0)

#define GLOADB(BBUF, H) do {                                            \
    _Pragma("unroll")                                                   \
    for (int n = 0; n < 4; ++n) {                                       \
        BBUF[n]     = *(const short8*)(bpl + (size_t)(2 * (H)) * 2048 + n * 512);     \
        BBUF[4 + n] = *(const short8*)(bpl + (size_t)(2 * (H) + 1) * 2048 + n * 512); \
    }                                                                   \
} while (0)

#define DSWRITE(RBUF, H) do {                                           \
    char* wb_ = ldsb + (((H) & 1) << 13);                               \
    _Pragma("unroll")                                                   \
    for (int t = 0; t < 8; ++t)                                         \
        *(f32x4*)(wb_ + t * 1024 + ((t & 1) ? wbase_o : wbase_e)) = RBUF[t]; \
} while (0)

#define COMPH(H, BBUF) do {                                             \
    const char* rb_ = ldsb + (((H) & 1) << 13);                         \
    _Pragma("unroll")                                                   \
    for (int q = 0; q < 2; ++q) {                                       \
        unsigned o0_ = q ? off10 : off00;                               \
        unsigned o1_ = q ? off11 : off01;                               \
        f32x4 a0 = *(const f32x4*)(rb_ + o0_);                          \
        f32x4 a1 = *(const f32x4*)(rb_ + o1_);                          \
        f32x4 d0 = *(const f32x4*)(rb_ + o0_ + 4096);                   \
        f32x4 d1 = *(const f32x4*)(rb_ + o1_ + 4096);                   \
        short8 afA, afB;                                                \
        afA[0] = (short)f2bf(a0[0]); afA[1] = (short)f2bf(a0[1]);       \
        afA[2] = (short)f2bf(a0[2]); afA[3] = (short)f2bf(a0[3]);       \
        afA[4] = (short)f2bf(a1[0]); afA[5] = (short)f2bf(a1[1]);       \
        afA[6] = (short)f2bf(a1[2]); afA[7] = (short)f2bf(a1[3]);       \
        afB[0] = (short)f2bf(d0[0]); afB[1] = (short)f2bf(d0[1]);       \
        afB[2] = (short)f2bf(d0[2]); afB[3] = (short)f2bf(d0[3]);       \
        afB[4] = (short)f2bf(d1[0]); afB[5] = (short)f2bf(d1[1]);       \
        afB[6] = (short)f2bf(d1[2]); afB[7] = (short)f2bf(d1[3]);       \
        acc[0][0] = __builtin_amdgcn_mfma_f32_16x16x32_bf16(afA, BBUF[q * 4 + 0], acc[0][0], 0, 0, 0); \
        acc[0][1] = __builtin_amdgcn_mfma_f32_16x16x32_bf16(afA, BBUF[q * 4 + 1], acc[0][1], 0, 0, 0); \
        acc[0][2] = __builtin_amdgcn_mfma_f32_16x16x32_bf16(afA, BBUF[q * 4 + 2], acc[0][2], 0, 0, 0); \
        acc[0][3] = __builtin_amdgcn_mfma_f32_16x16x32_bf16(afA, BBUF[q * 4 + 3], acc[0][3], 0, 0, 0); \
        acc[1][0] = __builtin_amdgcn_mfma_f32_16x16x32_bf16(afB, BBUF[q * 4 + 0], acc[1][0], 0, 0, 0); \
        acc[1][1] = __builtin_amdgcn_mfma_f32_16x16x32_bf16(afB, BBUF[q * 4 + 1], acc[1][1], 0, 0, 0); \
        acc[1][2] = __builtin_amdgcn_mfma_f32_16x16x32_bf16(afB, BBUF[q * 4 + 2], acc[1][2], 0, 0, 0); \
        acc[1][3] = __builtin_amdgcn_mfma_f32_16x16x32_bf16(afB, BBUF[q * 4 + 3], acc[1][3], 0, 0, 0); \
    }                                                                   \
} while (0)

__global__ __launch_bounds__(256, 2) void score_kernel(
    const float* __restrict__ mem,
    const unsigned short* __restrict__ Wf,
    const float* __restrict__ constv,
    const float* __restrict__ dlut,
    const float* __restrict__ clut,
    const float* __restrict__ W2,
    const float* __restrict__ b2p,
    const int* __restrict__ entc,
    const int* __restrict__ lms,
    const int* __restrict__ msp,
    float* __restrict__ out) {

    __shared__ __align__(16) char lds_raw[4][16384];   // 16 KB per wave (2 x 8 KB halves)

    int wave = threadIdx.x >> 6;
    int lane = threadIdx.x & 63;
    int g  = lane >> 4;     // 0..3
    int c0 = lane & 15;     // 0..15
    int row0 = blockIdx.x * 128 + wave * 32;    // wave's first row (32 rows)

    if (blockIdx.x == 0 && threadIdx.x == 0) out[MROWS] = 0.0f;  // dummy new-cluster score

    char* ldsb = &lds_raw[wave][0];

    // --- staging lane roles: instruction t covers LDS rows 4t..4t+3,
    //     lane i -> row 4t+(i>>4), inner (i&15)*16  (contiguous 1-KB span)
    int subrow = lane >> 4;
    int piece  = lane & 15;
    const char* gA = (const char*)(mem + (size_t)(row0 + subrow) * DD) + piece * 16;
    unsigned wbase_e = (unsigned)(subrow * 256 + ((piece * 16) ^ ((subrow & 7) << 4)));       // t even
    unsigned wbase_o = (unsigned)(subrow * 256 + ((piece * 16) ^ (((4 + subrow) & 7) << 4))); // t odd

    // --- fragment read offsets (row = rs*16 + c0; byte = q*128 + h64*64 + g*16, XOR-swizzled)
    unsigned swzr  = (unsigned)((c0 & 7) << 4);
    unsigned off00 = (unsigned)(c0 * 256 + ((0   + 0  + g * 16) ^ swzr));
    unsigned off01 = (unsigned)(c0 * 256 + ((0   + 64 + g * 16) ^ swzr));
    unsigned off10 = (unsigned)(c0 * 256 + ((128 + 0  + g * 16) ^ swzr));
    unsigned off11 = (unsigned)(c0 * 256 + ((128 + 64 + g * 16) ^ swzr));

    const unsigned short* bpl = Wf + lane * 8;

    f32x4 acc[2][4];
    #pragma unroll
    for (int r = 0; r < 2; ++r)
        #pragma unroll
        for (int t = 0; t < 4; ++t)
            acc[r][t] = (f32x4){0.f, 0.f, 0.f, 0.f};

    f32x4 rA[8], rB[8];
    short8 bA[8], bB[8];

    // --- software pipeline over 12 halves (issue order keeps every consumer
    //     wait from draining a younger prefetch: A two ahead, B one ahead)
    GLOADA(rA, 0);
    GLOADA(rB, 1);
    GLOADB(bA, 0);
    DSWRITE(rA, 0);

    GLOADA(rA, 2);  GLOADB(bB, 1);  DSWRITE(rB, 1);  COMPH(0, bA);
    GLOADA(rB, 3);  GLOADB(bA, 2);  DSWRITE(rA, 2);  COMPH(1, bB);
    GLOADA(rA, 4);  GLOADB(bB, 3);  DSWRITE(rB, 3);  COMPH(2, bA);
    GLOADA(rB, 5);  GLOADB(bA, 4);  DSWRITE(rA, 4);  COMPH(3, bB);
    GLOADA(rA, 6);  GLOADB(bB, 5);  DSWRITE(rB, 5);  COMPH(4, bA);
    GLOADA(rB, 7);  GLOADB(bA, 6);  DSWRITE(rA, 6);  COMPH(5, bB);
    GLOADA(rA, 8);  GLOADB(bB, 7);  DSWRITE(rB, 7);  COMPH(6, bA);
    GLOADA(rB, 9);  GLOADB(bA, 8);  DSWRITE(rA, 8);  COMPH(7, bB);
    GLOADA(rA, 10); GLOADB(bB, 9);  DSWRITE(rB, 9);  COMPH(8, bA);
    GLOADA(rB, 11); GLOADB(bA, 10); DSWRITE(rA, 10); COMPH(9, bB);
                    GLOADB(bB, 11); DSWRITE(rB, 11); COMPH(10, bA);
                                                     COMPH(11, bB);

    // Epilogue. D layout (m89): col = lane&15 (h-tile col), row = g*4 + reg.
    int ms  = msp[0];
    float b2v = b2p[0];
    float cv[4], w2[4];
    #pragma unroll
    for (int t = 0; t < 4; ++t) {
        cv[t] = constv[t * 16 + c0];
        w2[t] = W2[t * 16 + c0];
    }

    #pragma unroll
    for (int r = 0; r < 2; ++r) {
        #pragma unroll
        for (int i = 0; i < 4; ++i) {
            int row = row0 + r * 16 + g * 4 + i;
            int c    = entc[row];
            int dist = ms - lms[row];
            int db = bucket(dist);
            int cb = bucket(c);
            float part = 0.f;
            #pragma unroll
            for (int t = 0; t < 4; ++t) {
                float a = acc[r][t][i];
                int hc = t * 16 + c0;
                float h = a + cv[t] + dlut[db * 64 + hc] + clut[cb * 64 + hc];
                h = fmaxf(h, 0.f);
                part += h * w2[t];
            }
            part += __shfl_xor(part, 8, 64);
            part += __shfl_xor(part, 4, 64);
            part += __shfl_xor(part, 2, 64);
            part += __shfl_xor(part, 1, 64);
            if (c0 == 0)
                out[row] = (c > 0) ? (part + b2v) : -10000.0f;
        }
    }
}

extern "C" void kernel_launch(void* const* d_in, const int* in_sizes, int n_in,
                              void* d_out, int out_size, void* d_ws, size_t ws_size,
                              hipStream_t stream) {
    const float* ment   = (const float*)d_in[0];
    const float* mem    = (const float*)d_in[1];
    const float* dist_t = (const float*)d_in[2];
    const float* cnt_t  = (const float*)d_in[3];
    const float* W1     = (const float*)d_in[4];
    const float* b1     = (const float*)d_in[5];
    const float* W2     = (const float*)d_in[6];
    const float* b2     = (const float*)d_in[7];
    const int*   entc   = (const int*)d_in[8];
    const int*   lmsp   = (const int*)d_in[9];
    const int*   msp    = (const int*)d_in[10];

    unsigned short* Wf = (unsigned short*)d_ws;
    float* constv = (float*)((char*)d_ws + 98304);
    float* dlut   = constv + 64;
    float* clut   = dlut + 640;

    precompute_kernel<<<27, 1024, 0, stream>>>(ment, dist_t, cnt_t, W1, b1, Wf, constv, dlut, clut);
    score_kernel<<<512, 256, 0, stream>>>(mem, Wf, constv, dlut, clut, W2, b2,
                                          entc, lmsp, msp, (float*)d_out);
}